// Round 1
// baseline (589.884 us; speedup 1.0000x reference)
//
#include <hip/hip_runtime.h>

// ---------------------------------------------------------------------------
// Self-attention (B=4, N=2048, D=1024) on MI355X.
// Strategy: bf16 hi+lo split-precision MFMA for Q/K path (scores need fp32-like
// accuracy because softmax is sharp), plain bf16 for P@V.
// ---------------------------------------------------------------------------

typedef short bfx8 __attribute__((ext_vector_type(8)));
typedef float fx4 __attribute__((ext_vector_type(4)));
typedef unsigned short usx4 __attribute__((ext_vector_type(4)));

#define BM 128
#define BN 128
#define BK 32

// bf16 <-> f32 with round-to-nearest-even, no __hip_bfloat16 dependency
__device__ __forceinline__ unsigned short f2bf(float f) {
    unsigned u = __float_as_uint(f);
    u = (u + 0x7FFF + ((u >> 16) & 1)) >> 16;
    return (unsigned short)u;
}
__device__ __forceinline__ float bf2f(unsigned short u) {
    return __uint_as_float(((unsigned)u) << 16);
}

__device__ __forceinline__ void load_lds16(const void* g, void* l) {
    __builtin_amdgcn_global_load_lds(
        (const __attribute__((address_space(1))) void*)g,
        (__attribute__((address_space(3))) void*)l, 16, 0, 0);
}

// ---------------------------------------------------------------------------
// Elementwise: split fp32 -> bf16 hi + bf16 lo
// ---------------------------------------------------------------------------
__global__ __launch_bounds__(256) void split_kernel(
    const float4* __restrict__ in, usx4* __restrict__ hi, usx4* __restrict__ lo, int n4)
{
    int i = blockIdx.x * 256 + threadIdx.x;
    if (i >= n4) return;
    float4 v = in[i];
    float vv[4] = {v.x, v.y, v.z, v.w};
    usx4 h, l;
#pragma unroll
    for (int j = 0; j < 4; ++j) {
        unsigned short hb = f2bf(vv[j]);
        h[j] = hb;
        l[j] = f2bf(vv[j] - bf2f(hb));
    }
    hi[i] = h;
    lo[i] = l;
}

// ---------------------------------------------------------------------------
// Tiled GEMM: C[M x N] = alpha * (A[M x K] @ Bt[N x K]^T) + bias
// A, Bt given as bf16 (hi) or split (hi,lo) pairs.  SPLIT => 3 MFMAs/frag.
// OMODE 0: write fp32 to outF (ldc)
// OMODE 1: write split bf16 (outH, outL) at ldc  (for Q, K)
// OMODE 2: write bf16 TRANSPOSED V-layout: outH[(b*1024+col)*2048 + (row%2048)]
// ---------------------------------------------------------------------------
template <bool SPLIT, int OMODE>
__global__ __launch_bounds__(256) void gemm_kernel(
    const unsigned short* __restrict__ Ah, const unsigned short* __restrict__ Al,
    const unsigned short* __restrict__ Bh, const unsigned short* __restrict__ Bl,
    const float* __restrict__ bias,
    float* __restrict__ outF, unsigned short* __restrict__ outH, unsigned short* __restrict__ outL,
    int M, int N, int K, int lda, int ldb, int ldc, float alpha)
{
    __shared__ __attribute__((aligned(16))) unsigned short lAh[BM * BK];
    __shared__ __attribute__((aligned(16))) unsigned short lBh[BN * BK];
    __shared__ __attribute__((aligned(16))) unsigned short lAl[SPLIT ? BM * BK : 8];
    __shared__ __attribute__((aligned(16))) unsigned short lBl[SPLIT ? BN * BK : 8];

    const int tid = threadIdx.x;
    const int lane = tid & 63;
    const int wv = tid >> 6;            // wave 0..3
    const int wr = wv >> 1, wc = wv & 1; // 2x2 wave grid, each wave 64x64 out
    const int lr = lane & 15;           // frag row (A) / col (B,D)
    const int lk = lane >> 4;           // k-group 0..3

    const long m0 = (long)blockIdx.y * BM;
    const long n0 = (long)blockIdx.x * BN;

    fx4 acc[4][4] = {};

    for (int kk = 0; kk < K; kk += BK) {
        // ---- stage tiles to LDS: 512 chunks of 16B per tile, 2 per thread
#pragma unroll
        for (int i = 0; i < 2; ++i) {
            int c = i * 256 + tid;
            int row = c >> 2;
            int cw = (c & 3) * 8;  // element offset within 32-elem row
            load_lds16(Ah + (m0 + row) * (long)lda + kk + cw, &lAh[c * 8]);
            load_lds16(Bh + (n0 + row) * (long)ldb + kk + cw, &lBh[c * 8]);
            if constexpr (SPLIT) {
                load_lds16(Al + (m0 + row) * (long)lda + kk + cw, &lAl[c * 8]);
                load_lds16(Bl + (n0 + row) * (long)ldb + kk + cw, &lBl[c * 8]);
            }
        }
        __syncthreads();

        // ---- fragments
        bfx8 ah[4], bh[4], al[4], bl[4];
#pragma unroll
        for (int f = 0; f < 4; ++f) {
            ah[f] = *(const bfx8*)&lAh[(wr * 64 + f * 16 + lr) * BK + lk * 8];
            bh[f] = *(const bfx8*)&lBh[(wc * 64 + f * 16 + lr) * BK + lk * 8];
            if constexpr (SPLIT) {
                al[f] = *(const bfx8*)&lAl[(wr * 64 + f * 16 + lr) * BK + lk * 8];
                bl[f] = *(const bfx8*)&lBl[(wc * 64 + f * 16 + lr) * BK + lk * 8];
            }
        }
        // ---- MFMA
#pragma unroll
        for (int fm = 0; fm < 4; ++fm)
#pragma unroll
            for (int fn = 0; fn < 4; ++fn) {
                acc[fm][fn] = __builtin_amdgcn_mfma_f32_16x16x32_bf16(ah[fm], bh[fn], acc[fm][fn], 0, 0, 0);
                if constexpr (SPLIT) {
                    acc[fm][fn] = __builtin_amdgcn_mfma_f32_16x16x32_bf16(ah[fm], bl[fn], acc[fm][fn], 0, 0, 0);
                    acc[fm][fn] = __builtin_amdgcn_mfma_f32_16x16x32_bf16(al[fm], bh[fn], acc[fm][fn], 0, 0, 0);
                }
            }
        __syncthreads();
    }

    // ---- epilogue.  D frag: col = lane&15, row = (lane>>4)*4 + j
#pragma unroll
    for (int fm = 0; fm < 4; ++fm) {
#pragma unroll
        for (int fn = 0; fn < 4; ++fn) {
            const long row0 = m0 + wr * 64 + fm * 16 + lk * 4;
            const long col = n0 + wc * 64 + fn * 16 + lr;
            const float bb = bias ? bias[col] : 0.0f;
            if constexpr (OMODE == 2) {
                const long b = row0 >> 11;       // batch (rows are b*2048+n)
                const long nn = row0 & 2047;
                usx4 pk;
#pragma unroll
                for (int j = 0; j < 4; ++j) pk[j] = f2bf(alpha * acc[fm][fn][j] + bb);
                *(usx4*)&outH[(b * 1024 + col) * 2048 + nn] = pk;
            } else {
#pragma unroll
                for (int j = 0; j < 4; ++j) {
                    float v = alpha * acc[fm][fn][j] + bb;
                    long idx = (row0 + j) * (long)ldc + col;
                    if constexpr (OMODE == 0) {
                        outF[idx] = v;
                    } else {
                        unsigned short h = f2bf(v);
                        outH[idx] = h;
                        outL[idx] = f2bf(v - bf2f(h));
                    }
                }
            }
        }
    }
}

// ---------------------------------------------------------------------------
// Row softmax over 2048 fp32, write bf16 probs IN PLACE (row pitch stays 8KB,
// so P has element-ld 4096).  One block (256 thr) per row.
// ---------------------------------------------------------------------------
__global__ __launch_bounds__(256) void softmax_kernel(float* __restrict__ S)
{
    const long row = blockIdx.x;
    float* r = S + row * 2048;
    const int t = threadIdx.x;

    float4 v0 = *(const float4*)&r[t * 4];
    float4 v1 = *(const float4*)&r[1024 + t * 4];
    float v[8] = {v0.x, v0.y, v0.z, v0.w, v1.x, v1.y, v1.z, v1.w};

    float mx = v[0];
#pragma unroll
    for (int j = 1; j < 8; ++j) mx = fmaxf(mx, v[j]);
#pragma unroll
    for (int o = 32; o; o >>= 1) mx = fmaxf(mx, __shfl_xor(mx, o, 64));

    __shared__ float redm[4];
    __shared__ float reds[4];
    const int w = t >> 6;
    if ((t & 63) == 0) redm[w] = mx;
    __syncthreads();
    mx = fmaxf(fmaxf(redm[0], redm[1]), fmaxf(redm[2], redm[3]));

    float e[8];
    float s = 0.f;
#pragma unroll
    for (int j = 0; j < 8; ++j) {
        e[j] = __expf(v[j] - mx);
        s += e[j];
    }
#pragma unroll
    for (int o = 32; o; o >>= 1) s += __shfl_xor(s, o, 64);
    if ((t & 63) == 0) reds[w] = s;
    __syncthreads();
    s = reds[0] + reds[1] + reds[2] + reds[3];

    const float inv = 1.0f / s;
    usx4 p0, p1;
#pragma unroll
    for (int j = 0; j < 4; ++j) {
        p0[j] = f2bf(e[j] * inv);
        p1[j] = f2bf(e[4 + j] * inv);
    }
    unsigned short* pr = (unsigned short*)r;
    *(usx4*)&pr[t * 4] = p0;
    *(usx4*)&pr[1024 + t * 4] = p1;
}

// ---------------------------------------------------------------------------
extern "C" void kernel_launch(void* const* d_in, const int* in_sizes, int n_in,
                              void* d_out, int out_size, void* d_ws, size_t ws_size,
                              hipStream_t stream)
{
    const float* x  = (const float*)d_in[0];
    const float* Wq = (const float*)d_in[1];
    const float* bq = (const float*)d_in[2];
    const float* Wk = (const float*)d_in[3];
    const float* bk = (const float*)d_in[4];
    const float* Wv = (const float*)d_in[5];
    const float* bv = (const float*)d_in[6];
    float* out = (float*)d_out;

    const size_t SZ_X = 8192ull * 1024;  // x / Q / K / V element count
    const size_t SZ_W = 1024ull * 1024;

    unsigned short* xh  = (unsigned short*)d_ws;
    unsigned short* xl  = xh + SZ_X;
    unsigned short* Wqh = xl + SZ_X;
    unsigned short* Wql = Wqh + SZ_W;
    unsigned short* Wkh = Wql + SZ_W;
    unsigned short* Wkl = Wkh + SZ_W;
    unsigned short* Wvh = Wkl + SZ_W;
    unsigned short* Wvl = Wvh + SZ_W;
    unsigned short* Qh  = Wvl + SZ_W;
    unsigned short* Ql  = Qh + SZ_X;
    unsigned short* Kh  = Ql + SZ_X;
    unsigned short* Kl  = Kh + SZ_X;
    unsigned short* Vt  = Kl + SZ_X;            // [4][1024][2048] bf16
    float* S            = (float*)(Vt + SZ_X);  // [2048][2048] fp32, reused per batch

    dim3 blk(256);

    // 1) precision splits
    split_kernel<<<(int)(SZ_X / 4 / 256), blk, 0, stream>>>((const float4*)x, (usx4*)xh, (usx4*)xl, (int)(SZ_X / 4));
    split_kernel<<<(int)(SZ_W / 4 / 256), blk, 0, stream>>>((const float4*)Wq, (usx4*)Wqh, (usx4*)Wql, (int)(SZ_W / 4));
    split_kernel<<<(int)(SZ_W / 4 / 256), blk, 0, stream>>>((const float4*)Wk, (usx4*)Wkh, (usx4*)Wkl, (int)(SZ_W / 4));
    split_kernel<<<(int)(SZ_W / 4 / 256), blk, 0, stream>>>((const float4*)Wv, (usx4*)Wvh, (usx4*)Wvl, (int)(SZ_W / 4));

    // 2) projections: Q,K split-out; V transposed bf16
    gemm_kernel<true, 1><<<dim3(1024 / BN, 8192 / BM), blk, 0, stream>>>(
        xh, xl, Wqh, Wql, bq, nullptr, Qh, Ql, 8192, 1024, 1024, 1024, 1024, 1024, 1.0f);
    gemm_kernel<true, 1><<<dim3(1024 / BN, 8192 / BM), blk, 0, stream>>>(
        xh, xl, Wkh, Wkl, bk, nullptr, Kh, Kl, 8192, 1024, 1024, 1024, 1024, 1024, 1.0f);
    gemm_kernel<true, 2><<<dim3(1024 / BN, 8192 / BM), blk, 0, stream>>>(
        xh, xl, Wvh, Wvl, bv, nullptr, Vt, nullptr, 8192, 1024, 1024, 1024, 1024, 0, 1.0f);

    // 3) per-batch attention (S buffer reused; stream-ordered)
    for (int b = 0; b < 4; ++b) {
        const size_t qo = (size_t)b * 2048 * 1024;
        gemm_kernel<true, 0><<<dim3(2048 / BN, 2048 / BM), blk, 0, stream>>>(
            Qh + qo, Ql + qo, Kh + qo, Kl + qo, nullptr, S, nullptr, nullptr,
            2048, 2048, 1024, 1024, 1024, 2048, 1.0f);
        softmax_kernel<<<2048, blk, 0, stream>>>(S);
        gemm_kernel<false, 0><<<dim3(1024 / BN, 2048 / BM), blk, 0, stream>>>(
            (const unsigned short*)S, nullptr, Vt + (size_t)b * 1024 * 2048, nullptr, nullptr,
            out + qo, nullptr, nullptr,
            2048, 1024, 2048, 4096, 2048, 1024, 0.03125f);
    }
}

// Round 2
// 374.508 us; speedup vs baseline: 1.5751x; 1.5751x over previous
//
#include <hip/hip_runtime.h>

// ---------------------------------------------------------------------------
// Self-attention (B=4, N=2048, D=1024) on MI355X.
// bf16 hi+lo split-precision MFMA for the Q/K path, plain bf16 for V and P@V.
// Round 1: z-batched dispatches (scores/softmax/PV over all 4 batches),
// merged Q+K projection, non-split V projection.
// ---------------------------------------------------------------------------

typedef short bfx8 __attribute__((ext_vector_type(8)));
typedef float fx4 __attribute__((ext_vector_type(4)));
typedef unsigned short usx4 __attribute__((ext_vector_type(4)));

#define BM 128
#define BN 128
#define BK 32

__device__ __forceinline__ unsigned short f2bf(float f) {
    unsigned u = __float_as_uint(f);
    u = (u + 0x7FFF + ((u >> 16) & 1)) >> 16;
    return (unsigned short)u;
}
__device__ __forceinline__ float bf2f(unsigned short u) {
    return __uint_as_float(((unsigned)u) << 16);
}

__device__ __forceinline__ void load_lds16(const void* g, void* l) {
    __builtin_amdgcn_global_load_lds(
        (const __attribute__((address_space(1))) void*)g,
        (__attribute__((address_space(3))) void*)l, 16, 0, 0);
}

// ---------------------------------------------------------------------------
// Elementwise: split fp32 -> bf16 hi + bf16 lo
// ---------------------------------------------------------------------------
__global__ __launch_bounds__(256) void split_kernel(
    const float4* __restrict__ in, usx4* __restrict__ hi, usx4* __restrict__ lo, int n4)
{
    int i = blockIdx.x * 256 + threadIdx.x;
    if (i >= n4) return;
    float4 v = in[i];
    float vv[4] = {v.x, v.y, v.z, v.w};
    usx4 h, l;
#pragma unroll
    for (int j = 0; j < 4; ++j) {
        unsigned short hb = f2bf(vv[j]);
        h[j] = hb;
        l[j] = f2bf(vv[j] - bf2f(hb));
    }
    hi[i] = h;
    lo[i] = l;
}

// ---------------------------------------------------------------------------
// Tiled GEMM: C[M x N] = alpha * (A[M x K] @ Bt[N x K]^T) + bias
// z-batched via blockIdx.z with element strides sAz/sBz/sCz.
// SPLIT => hi+lo operands, 3 MFMAs/frag.
// OMODE 0: fp32 out to outF (+ z*sCz)
// OMODE 1: split bf16 out to outH/outL (+ z*sCz); bias = z ? bias1 : bias0
// OMODE 2: bf16 TRANSPOSED V-layout: outH[(b*1024+col)*2048 + (row%2048)]
// ---------------------------------------------------------------------------
template <bool SPLIT, int OMODE>
__global__ __launch_bounds__(256) void gemm_kernel(
    const unsigned short* __restrict__ Ah, const unsigned short* __restrict__ Al,
    const unsigned short* __restrict__ Bh, const unsigned short* __restrict__ Bl,
    const float* __restrict__ bias0, const float* __restrict__ bias1,
    float* __restrict__ outF, unsigned short* __restrict__ outH, unsigned short* __restrict__ outL,
    int M, int N, int K, int lda, int ldb, int ldc, float alpha,
    long sAz, long sBz, long sCz)
{
    __shared__ __attribute__((aligned(16))) unsigned short lAh[BM * BK];
    __shared__ __attribute__((aligned(16))) unsigned short lBh[BN * BK];
    __shared__ __attribute__((aligned(16))) unsigned short lAl[SPLIT ? BM * BK : 8];
    __shared__ __attribute__((aligned(16))) unsigned short lBl[SPLIT ? BN * BK : 8];

    const int z = blockIdx.z;
    Ah += (long)z * sAz;
    Bh += (long)z * sBz;
    if constexpr (SPLIT) {
        Al += (long)z * sAz;
        Bl += (long)z * sBz;
    }
    const float* bias = (OMODE == 1 && z == 1) ? bias1 : bias0;

    const int tid = threadIdx.x;
    const int lane = tid & 63;
    const int wv = tid >> 6;
    const int wr = wv >> 1, wc = wv & 1;
    const int lr = lane & 15;
    const int lk = lane >> 4;

    const long m0 = (long)blockIdx.y * BM;
    const long n0 = (long)blockIdx.x * BN;

    fx4 acc[4][4] = {};

    for (int kk = 0; kk < K; kk += BK) {
#pragma unroll
        for (int i = 0; i < 2; ++i) {
            int c = i * 256 + tid;
            int row = c >> 2;
            int cw = (c & 3) * 8;
            load_lds16(Ah + (m0 + row) * (long)lda + kk + cw, &lAh[c * 8]);
            load_lds16(Bh + (n0 + row) * (long)ldb + kk + cw, &lBh[c * 8]);
            if constexpr (SPLIT) {
                load_lds16(Al + (m0 + row) * (long)lda + kk + cw, &lAl[c * 8]);
                load_lds16(Bl + (n0 + row) * (long)ldb + kk + cw, &lBl[c * 8]);
            }
        }
        __syncthreads();

        bfx8 ah[4], bh[4], al[4], bl[4];
#pragma unroll
        for (int f = 0; f < 4; ++f) {
            ah[f] = *(const bfx8*)&lAh[(wr * 64 + f * 16 + lr) * BK + lk * 8];
            bh[f] = *(const bfx8*)&lBh[(wc * 64 + f * 16 + lr) * BK + lk * 8];
            if constexpr (SPLIT) {
                al[f] = *(const bfx8*)&lAl[(wr * 64 + f * 16 + lr) * BK + lk * 8];
                bl[f] = *(const bfx8*)&lBl[(wc * 64 + f * 16 + lr) * BK + lk * 8];
            }
        }
#pragma unroll
        for (int fm = 0; fm < 4; ++fm)
#pragma unroll
            for (int fn = 0; fn < 4; ++fn) {
                acc[fm][fn] = __builtin_amdgcn_mfma_f32_16x16x32_bf16(ah[fm], bh[fn], acc[fm][fn], 0, 0, 0);
                if constexpr (SPLIT) {
                    acc[fm][fn] = __builtin_amdgcn_mfma_f32_16x16x32_bf16(ah[fm], bl[fn], acc[fm][fn], 0, 0, 0);
                    acc[fm][fn] = __builtin_amdgcn_mfma_f32_16x16x32_bf16(al[fm], bh[fn], acc[fm][fn], 0, 0, 0);
                }
            }
        __syncthreads();
    }

    // epilogue.  D frag: col = lane&15, row = (lane>>4)*4 + j
#pragma unroll
    for (int fm = 0; fm < 4; ++fm) {
#pragma unroll
        for (int fn = 0; fn < 4; ++fn) {
            const long row0 = m0 + wr * 64 + fm * 16 + lk * 4;
            const long col = n0 + wc * 64 + fn * 16 + lr;
            const float bb = bias ? bias[col] : 0.0f;
            if constexpr (OMODE == 2) {
                const long b = row0 >> 11;
                const long nn = row0 & 2047;
                usx4 pk;
#pragma unroll
                for (int j = 0; j < 4; ++j) pk[j] = f2bf(alpha * acc[fm][fn][j] + bb);
                *(usx4*)&outH[(b * 1024 + col) * 2048 + nn] = pk;
            } else {
#pragma unroll
                for (int j = 0; j < 4; ++j) {
                    float v = alpha * acc[fm][fn][j] + bb;
                    long idx = (row0 + j) * (long)ldc + col;
                    if constexpr (OMODE == 0) {
                        outF[(long)z * sCz + idx] = v;
                    } else {
                        unsigned short h = f2bf(v);
                        outH[(long)z * sCz + idx] = h;
                        outL[(long)z * sCz + idx] = f2bf(v - bf2f(h));
                    }
                }
            }
        }
    }
}

// ---------------------------------------------------------------------------
// Row softmax over 2048 fp32, write bf16 probs IN PLACE. One block per row.
// ---------------------------------------------------------------------------
__global__ __launch_bounds__(256) void softmax_kernel(float* __restrict__ S)
{
    const long row = blockIdx.x;
    float* r = S + row * 2048;
    const int t = threadIdx.x;

    float4 v0 = *(const float4*)&r[t * 4];
    float4 v1 = *(const float4*)&r[1024 + t * 4];
    float v[8] = {v0.x, v0.y, v0.z, v0.w, v1.x, v1.y, v1.z, v1.w};

    float mx = v[0];
#pragma unroll
    for (int j = 1; j < 8; ++j) mx = fmaxf(mx, v[j]);
#pragma unroll
    for (int o = 32; o; o >>= 1) mx = fmaxf(mx, __shfl_xor(mx, o, 64));

    __shared__ float redm[4];
    __shared__ float reds[4];
    const int w = t >> 6;
    if ((t & 63) == 0) redm[w] = mx;
    __syncthreads();
    mx = fmaxf(fmaxf(redm[0], redm[1]), fmaxf(redm[2], redm[3]));

    float e[8];
    float s = 0.f;
#pragma unroll
    for (int j = 0; j < 8; ++j) {
        e[j] = __expf(v[j] - mx);
        s += e[j];
    }
#pragma unroll
    for (int o = 32; o; o >>= 1) s += __shfl_xor(s, o, 64);
    if ((t & 63) == 0) reds[w] = s;
    __syncthreads();
    s = reds[0] + reds[1] + reds[2] + reds[3];

    const float inv = 1.0f / s;
    usx4 p0, p1;
#pragma unroll
    for (int j = 0; j < 4; ++j) {
        p0[j] = f2bf(e[j] * inv);
        p1[j] = f2bf(e[4 + j] * inv);
    }
    unsigned short* pr = (unsigned short*)r;
    *(usx4*)&pr[t * 4] = p0;
    *(usx4*)&pr[1024 + t * 4] = p1;
}

// ---------------------------------------------------------------------------
extern "C" void kernel_launch(void* const* d_in, const int* in_sizes, int n_in,
                              void* d_out, int out_size, void* d_ws, size_t ws_size,
                              hipStream_t stream)
{
    const float* x  = (const float*)d_in[0];
    const float* Wq = (const float*)d_in[1];
    const float* bq = (const float*)d_in[2];
    const float* Wk = (const float*)d_in[3];
    const float* bk = (const float*)d_in[4];
    const float* Wv = (const float*)d_in[5];
    const float* bv = (const float*)d_in[6];
    float* out = (float*)d_out;

    const size_t SZ_X = 8192ull * 1024;
    const size_t SZ_W = 1024ull * 1024;

    unsigned short* xh  = (unsigned short*)d_ws;
    unsigned short* xl  = xh + SZ_X;
    unsigned short* Wqh = xl + SZ_X;
    unsigned short* Wql = Wqh + SZ_W;
    unsigned short* Wkh = Wql + SZ_W;
    unsigned short* Wkl = Wkh + SZ_W;
    unsigned short* Wvh = Wkl + SZ_W;
    unsigned short* Wvl = Wvh + SZ_W;
    unsigned short* Qh  = Wvl + SZ_W;
    unsigned short* Ql  = Qh + SZ_X;
    unsigned short* Kh  = Ql + SZ_X;
    unsigned short* Kl  = Kh + SZ_X;
    unsigned short* Vt  = Kl + SZ_X;            // [4][1024][2048] bf16
    float* S            = (float*)(Vt + SZ_X);  // [nb][2048][2048] fp32

    // bytes needed with fully-batched S (nb=4)
    const size_t BASE = ((char*)(Vt + SZ_X)) - (char*)d_ws;
    const size_t NEED4 = BASE + 4ull * 2048 * 2048 * 4;
    const int nb = (ws_size >= NEED4) ? 4 : 1;

    dim3 blk(256);

    // 1) precision splits
    split_kernel<<<(int)(SZ_X / 4 / 256), blk, 0, stream>>>((const float4*)x, (usx4*)xh, (usx4*)xl, (int)(SZ_X / 4));
    split_kernel<<<(int)(SZ_W / 4 / 256), blk, 0, stream>>>((const float4*)Wq, (usx4*)Wqh, (usx4*)Wql, (int)(SZ_W / 4));
    split_kernel<<<(int)(SZ_W / 4 / 256), blk, 0, stream>>>((const float4*)Wk, (usx4*)Wkh, (usx4*)Wkl, (int)(SZ_W / 4));
    split_kernel<<<(int)(SZ_W / 4 / 256), blk, 0, stream>>>((const float4*)Wv, (usx4*)Wvh, (usx4*)Wvl, (int)(SZ_W / 4));

    // 2) projections: Q+K merged (z=2, split-precision out); V plain bf16, transposed
    gemm_kernel<true, 1><<<dim3(1024 / BN, 8192 / BM, 2), blk, 0, stream>>>(
        xh, xl, Wqh, Wql, bq, bk, nullptr, Qh, Ql,
        8192, 1024, 1024, 1024, 1024, 1024, 1.0f,
        0L, (long)(2 * SZ_W), (long)(2 * SZ_X));
    gemm_kernel<false, 2><<<dim3(1024 / BN, 8192 / BM, 1), blk, 0, stream>>>(
        xh, nullptr, Wvh, nullptr, bv, nullptr, nullptr, Vt, nullptr,
        8192, 1024, 1024, 1024, 1024, 0, 1.0f, 0L, 0L, 0L);

    // 3) attention, z-batched over nb batches at a time
    for (int g = 0; g < 4; g += nb) {
        const size_t qo = (size_t)g * 2048 * 1024;
        gemm_kernel<true, 0><<<dim3(2048 / BN, 2048 / BM, nb), blk, 0, stream>>>(
            Qh + qo, Ql + qo, Kh + qo, Kl + qo, nullptr, nullptr, S, nullptr, nullptr,
            2048, 2048, 1024, 1024, 1024, 2048, 1.0f,
            2097152L, 2097152L, 4194304L);
        softmax_kernel<<<2048 * nb, blk, 0, stream>>>(S);
        gemm_kernel<false, 0><<<dim3(1024 / BN, 2048 / BM, nb), blk, 0, stream>>>(
            (const unsigned short*)S, nullptr, Vt + (size_t)g * 1024 * 2048, nullptr, nullptr, nullptr,
            out + qo, nullptr, nullptr,
            2048, 1024, 2048, 4096, 2048, 1024, 0.03125f,
            8388608L, 2097152L, 2097152L);
    }
}

// Round 3
// 366.877 us; speedup vs baseline: 1.6079x; 1.0208x over previous
//
#include <hip/hip_runtime.h>

// ---------------------------------------------------------------------------
// Self-attention (B=4, N=2048, D=1024) on MI355X — fp16 pipeline.
// x is split hi+lo fp16 (concat along K); W plain fp16. 2-term GEMMs are
// expressed as plain GEMMs with K'=2K and a k-mask that reuses the B tile.
// Scores accumulate fp32; softmax fp32; P stored fp16 in-place; PV plain fp16.
// ---------------------------------------------------------------------------

typedef _Float16 hfx8 __attribute__((ext_vector_type(8)));
typedef _Float16 hfx4 __attribute__((ext_vector_type(4)));
typedef float fx4 __attribute__((ext_vector_type(4)));

#define BM 128
#define BN 128
#define BK 32

__device__ __forceinline__ void load_lds16(const void* g, void* l) {
    __builtin_amdgcn_global_load_lds(
        (const __attribute__((address_space(1))) void*)g,
        (__attribute__((address_space(3))) void*)l, 16, 0, 0);
}

// ---------------------------------------------------------------------------
// x fp32 [8192][1024] -> xs fp16 [8192][2048], row = [hi(1024) | lo(1024)]
// ---------------------------------------------------------------------------
__global__ __launch_bounds__(256) void splitx_kernel(
    const float4* __restrict__ in, _Float16* __restrict__ xs)
{
    const int i = blockIdx.x * 256 + threadIdx.x;  // 0 .. 2M-1
    const long row = i >> 8;
    const int c4 = (i & 255) * 4;
    float4 v = in[i];
    float vv[4] = {v.x, v.y, v.z, v.w};
    hfx4 h, l;
#pragma unroll
    for (int j = 0; j < 4; ++j) {
        h[j] = (_Float16)vv[j];
        l[j] = (_Float16)(vv[j] - (float)h[j]);
    }
    *(hfx4*)&xs[row * 2048 + c4] = h;
    *(hfx4*)&xs[row * 2048 + 1024 + c4] = l;
}

// ---------------------------------------------------------------------------
// plain fp32 -> fp16 convert (weights)
// ---------------------------------------------------------------------------
__global__ __launch_bounds__(256) void convw_kernel(
    const float4* __restrict__ in, _Float16* __restrict__ out, int n4)
{
    const int i = blockIdx.x * 256 + threadIdx.x;
    if (i >= n4) return;
    float4 v = in[i];
    hfx4 h;
    h[0] = (_Float16)v.x; h[1] = (_Float16)v.y;
    h[2] = (_Float16)v.z; h[3] = (_Float16)v.w;
    *(hfx4*)&out[(long)i * 4] = h;
}

// ---------------------------------------------------------------------------
// Tiled fp16 GEMM: C[M x N] = alpha * (A[M x K'] @ Bt[N x K']^T) + bias
// B's k-index is (k & bmask): bmask = K-1 duplicates the B panel for 2-term
// split GEMMs; bmask = 0x7fffffff for plain.
// z-batched via blockIdx.z with element strides sAz/sBz/sCz.
// OMODE 0: fp32 out to outF
// OMODE 1: split fp16 out: hi at [row,col], lo at [row,col+1024]  (Q)
// OMODE 2: plain fp16 out                                        (K)
// OMODE 3: fp16 transposed V-layout: outH[(b*1024+col)*2048 + row%2048]
// ---------------------------------------------------------------------------
template <int OMODE>
__global__ __launch_bounds__(256) void gemm_kernel(
    const _Float16* __restrict__ A, const _Float16* __restrict__ B,
    const float* __restrict__ bias,
    float* __restrict__ outF, _Float16* __restrict__ outH,
    int M, int N, int K, int lda, int ldb, int ldc, int bmask, float alpha,
    long sAz, long sBz, long sCz)
{
    __shared__ __attribute__((aligned(16))) _Float16 lA[BM * BK];
    __shared__ __attribute__((aligned(16))) _Float16 lB[BN * BK];

    const int z = blockIdx.z;
    A += (long)z * sAz;
    B += (long)z * sBz;

    const int tid = threadIdx.x;
    const int lane = tid & 63;
    const int wv = tid >> 6;
    const int wr = wv >> 1, wc = wv & 1;   // 2x2 waves, 64x64 out each
    const int lr = lane & 15;
    const int lk = lane >> 4;

    const long m0 = (long)blockIdx.y * BM;
    const long n0 = (long)blockIdx.x * BN;

    fx4 acc[4][4] = {};

    for (int kk = 0; kk < K; kk += BK) {
        const int kb = kk & bmask;
#pragma unroll
        for (int i = 0; i < 2; ++i) {
            int c = i * 256 + tid;         // 0..511
            int row = c >> 2;
            int cw = (c & 3) * 8;
            load_lds16(A + (m0 + row) * (long)lda + kk + cw, &lA[c * 8]);
            load_lds16(B + (n0 + row) * (long)ldb + kb + cw, &lB[c * 8]);
        }
        __syncthreads();

        hfx8 af[4], bf[4];
#pragma unroll
        for (int f = 0; f < 4; ++f) {
            af[f] = *(const hfx8*)&lA[(wr * 64 + f * 16 + lr) * BK + lk * 8];
            bf[f] = *(const hfx8*)&lB[(wc * 64 + f * 16 + lr) * BK + lk * 8];
        }
#pragma unroll
        for (int fm = 0; fm < 4; ++fm)
#pragma unroll
            for (int fn = 0; fn < 4; ++fn)
                acc[fm][fn] = __builtin_amdgcn_mfma_f32_16x16x32_f16(af[fm], bf[fn], acc[fm][fn], 0, 0, 0);
        __syncthreads();
    }

    // epilogue. D frag: col = lane&15, row = (lane>>4)*4 + j
#pragma unroll
    for (int fm = 0; fm < 4; ++fm) {
#pragma unroll
        for (int fn = 0; fn < 4; ++fn) {
            const long row0 = m0 + wr * 64 + fm * 16 + lk * 4;
            const long col = n0 + wc * 64 + fn * 16 + lr;
            const float bb = bias ? bias[col] : 0.0f;
            if constexpr (OMODE == 3) {
                const long b = row0 >> 11;
                const long nn = row0 & 2047;
                hfx4 pk;
#pragma unroll
                for (int j = 0; j < 4; ++j) pk[j] = (_Float16)(alpha * acc[fm][fn][j] + bb);
                *(hfx4*)&outH[(b * 1024 + col) * 2048 + nn] = pk;
            } else {
#pragma unroll
                for (int j = 0; j < 4; ++j) {
                    float v = alpha * acc[fm][fn][j] + bb;
                    long idx = (row0 + j) * (long)ldc + col;
                    if constexpr (OMODE == 0) {
                        outF[(long)z * sCz + idx] = v;
                    } else if constexpr (OMODE == 1) {
                        _Float16 h = (_Float16)v;
                        outH[idx] = h;
                        outH[idx + 1024] = (_Float16)(v - (float)h);
                    } else {
                        outH[idx] = (_Float16)v;
                    }
                }
            }
        }
    }
}

// ---------------------------------------------------------------------------
// Row softmax over 2048 fp32, write fp16 probs IN PLACE (first 4KB of each
// 8KB row => P has element-ld 4096). One block (256 thr) per row.
// ---------------------------------------------------------------------------
__global__ __launch_bounds__(256) void softmax_kernel(float* __restrict__ S)
{
    const long row = blockIdx.x;
    float* r = S + row * 2048;
    const int t = threadIdx.x;

    float4 v0 = *(const float4*)&r[t * 4];
    float4 v1 = *(const float4*)&r[1024 + t * 4];
    float v[8] = {v0.x, v0.y, v0.z, v0.w, v1.x, v1.y, v1.z, v1.w};

    float mx = v[0];
#pragma unroll
    for (int j = 1; j < 8; ++j) mx = fmaxf(mx, v[j]);
#pragma unroll
    for (int o = 32; o; o >>= 1) mx = fmaxf(mx, __shfl_xor(mx, o, 64));

    __shared__ float redm[4];
    __shared__ float reds[4];
    const int w = t >> 6;
    if ((t & 63) == 0) redm[w] = mx;
    __syncthreads();
    mx = fmaxf(fmaxf(redm[0], redm[1]), fmaxf(redm[2], redm[3]));

    float e[8];
    float s = 0.f;
#pragma unroll
    for (int j = 0; j < 8; ++j) {
        e[j] = __expf(v[j] - mx);
        s += e[j];
    }
#pragma unroll
    for (int o = 32; o; o >>= 1) s += __shfl_xor(s, o, 64);
    if ((t & 63) == 0) reds[w] = s;
    __syncthreads();
    s = reds[0] + reds[1] + reds[2] + reds[3];

    const float inv = 1.0f / s;
    hfx4 p0, p1;
#pragma unroll
    for (int j = 0; j < 4; ++j) {
        p0[j] = (_Float16)(e[j] * inv);
        p1[j] = (_Float16)(e[4 + j] * inv);
    }
    _Float16* pr = (_Float16*)r;
    *(hfx4*)&pr[t * 4] = p0;
    *(hfx4*)&pr[1024 + t * 4] = p1;
}

// ---------------------------------------------------------------------------
extern "C" void kernel_launch(void* const* d_in, const int* in_sizes, int n_in,
                              void* d_out, int out_size, void* d_ws, size_t ws_size,
                              hipStream_t stream)
{
    const float* x  = (const float*)d_in[0];
    const float* Wq = (const float*)d_in[1];
    const float* bq = (const float*)d_in[2];
    const float* Wk = (const float*)d_in[3];
    const float* bk = (const float*)d_in[4];
    const float* Wv = (const float*)d_in[5];
    const float* bv = (const float*)d_in[6];
    float* out = (float*)d_out;

    // workspace layout (fp16 elements unless noted)
    _Float16* xs  = (_Float16*)d_ws;            // [8192][2048] = 32 MB
    _Float16* Wqh = xs + 8192ull * 2048;        // [1024][1024] = 2 MB
    _Float16* Wkh = Wqh + 1024ull * 1024;
    _Float16* Wvh = Wkh + 1024ull * 1024;
    _Float16* Qs  = Wvh + 1024ull * 1024;       // [4][2048][2048] = 32 MB ([Qh|Ql])
    _Float16* Ks  = Qs + 4ull * 2048 * 2048;    // [4][2048][1024] = 16 MB
    _Float16* Vt  = Ks + 4ull * 2048 * 1024;    // [4][1024][2048] = 16 MB
    float* S      = (float*)(Vt + 4ull * 1024 * 2048);  // [4][2048][2048] fp32 = 64 MB

    dim3 blk(256);
    const int NOMASK = 0x7fffffff;

    // 1) converts
    splitx_kernel<<<8192, blk, 0, stream>>>((const float4*)x, xs);
    convw_kernel<<<1024, blk, 0, stream>>>((const float4*)Wq, Wqh, 262144);
    convw_kernel<<<1024, blk, 0, stream>>>((const float4*)Wk, Wkh, 262144);
    convw_kernel<<<1024, blk, 0, stream>>>((const float4*)Wv, Wvh, 262144);

    // 2) projections
    // Q: [xh|xl] @ [Wq|Wq]^T (K'=2048, bmask=1023), split fp16 out
    gemm_kernel<1><<<dim3(1024 / BN, 8192 / BM, 1), blk, 0, stream>>>(
        xs, Wqh, bq, nullptr, Qs,
        8192, 1024, 2048, 2048, 1024, 2048, 1023, 1.0f, 0L, 0L, 0L);
    // K: same 2-term, plain fp16 out
    gemm_kernel<2><<<dim3(1024 / BN, 8192 / BM, 1), blk, 0, stream>>>(
        xs, Wkh, bk, nullptr, Ks,
        8192, 1024, 2048, 2048, 1024, 1024, 1023, 1.0f, 0L, 0L, 0L);
    // V: 1-term (reads only hi half of xs via K=1024), transposed fp16 out
    gemm_kernel<3><<<dim3(1024 / BN, 8192 / BM, 1), blk, 0, stream>>>(
        xs, Wvh, bv, nullptr, Vt,
        8192, 1024, 1024, 2048, 1024, 0, NOMASK, 1.0f, 0L, 0L, 0L);

    // 3) scores: [Qh|Ql] @ [K|K]^T  (K'=2048, bmask=1023), fp32 out, z=4
    gemm_kernel<0><<<dim3(2048 / BN, 2048 / BM, 4), blk, 0, stream>>>(
        Qs, Ks, nullptr, S, nullptr,
        2048, 2048, 2048, 2048, 1024, 2048, 1023, 1.0f,
        4194304L, 2097152L, 4194304L);

    // 4) softmax (P fp16 in place), z-batched over all rows
    softmax_kernel<<<2048 * 4, blk, 0, stream>>>(S);

    // 5) PV: P[2048 x 2048] @ Vt^T, alpha = 1/32, fp32 out, z=4
    gemm_kernel<0><<<dim3(1024 / BN, 2048 / BM, 4), blk, 0, stream>>>(
        (const _Float16*)S, Vt, nullptr, out, nullptr,
        2048, 1024, 2048, 4096, 2048, 1024, NOMASK, 0.03125f,
        8388608L, 2097152L, 2097152L);
}

// Round 4
// 279.283 us; speedup vs baseline: 2.1121x; 1.3136x over previous
//
#include <hip/hip_runtime.h>

// ---------------------------------------------------------------------------
// Self-attention (B=4, N=2048, D=1024) on MI355X — fp16 pipeline, round 4:
// 512-thread BK=64 double-buffered GEMM with counted vmcnt (T4), LDS XOR
// swizzle (T2), setprio (T5). Raw s_barrier only — no vmcnt(0) in main loop.
// ---------------------------------------------------------------------------

typedef _Float16 hfx8 __attribute__((ext_vector_type(8)));
typedef _Float16 hfx4 __attribute__((ext_vector_type(4)));
typedef float fx4 __attribute__((ext_vector_type(4)));

__device__ __forceinline__ void load_lds16(const void* g, void* l) {
    __builtin_amdgcn_global_load_lds(
        (const __attribute__((address_space(1))) void*)g,
        (__attribute__((address_space(3))) void*)l, 16, 0, 0);
}

template <int N> __device__ __forceinline__ void vmwait() {
    if constexpr (N == 8) asm volatile("s_waitcnt vmcnt(8)" ::: "memory");
    else if constexpr (N == 6) asm volatile("s_waitcnt vmcnt(6)" ::: "memory");
    else asm volatile("s_waitcnt vmcnt(0)" ::: "memory");
}

// ---------------------------------------------------------------------------
// x fp32 [8192][1024] -> xs fp16 [8192][2048], row = [hi(1024) | lo(1024)]
// ---------------------------------------------------------------------------
__global__ __launch_bounds__(256) void splitx_kernel(
    const float4* __restrict__ in, _Float16* __restrict__ xs)
{
    const int i = blockIdx.x * 256 + threadIdx.x;
    const long row = i >> 8;
    const int c4 = (i & 255) * 4;
    float4 v = in[i];
    float vv[4] = {v.x, v.y, v.z, v.w};
    hfx4 h, l;
#pragma unroll
    for (int j = 0; j < 4; ++j) {
        h[j] = (_Float16)vv[j];
        l[j] = (_Float16)(vv[j] - (float)h[j]);
    }
    *(hfx4*)&xs[row * 2048 + c4] = h;
    *(hfx4*)&xs[row * 2048 + 1024 + c4] = l;
}

__global__ __launch_bounds__(256) void convw_kernel(
    const float4* __restrict__ in, _Float16* __restrict__ out, int n4)
{
    const int i = blockIdx.x * 256 + threadIdx.x;
    if (i >= n4) return;
    float4 v = in[i];
    hfx4 h;
    h[0] = (_Float16)v.x; h[1] = (_Float16)v.y;
    h[2] = (_Float16)v.z; h[3] = (_Float16)v.w;
    *(hfx4*)&out[(long)i * 4] = h;
}

// ---------------------------------------------------------------------------
// Pipelined GEMM. BN=256, BK=64, 512 threads = 8 waves (2 M x 4 N).
// BM = 256 (proj/scores) or 128 (PV). LDS: 2 x (BM+256)x64 fp16 (128/96 KB).
// A [M x K'] row-major lda; B [N x K'] row-major ldb with k & bmask.
// OMODE 0: fp32 out = alpha*acc -> outF + z*sCz (ldc)
// OMODE 1: projections, z: 0 = Q split (oQ [8192][2048] hi|lo),
//          1 = K plain (oK [8192][1024]), 2 = V transposed (oV [4][1024][2048])
// ---------------------------------------------------------------------------
template <int BM, int OMODE>
__global__ __launch_bounds__(512, 2) void gemm2(
    const _Float16* __restrict__ A,
    const _Float16* __restrict__ Bq, const _Float16* __restrict__ Bk, const _Float16* __restrict__ Bv,
    const float* __restrict__ bq, const float* __restrict__ bk, const float* __restrict__ bv,
    float* __restrict__ outF, _Float16* __restrict__ oQ, _Float16* __restrict__ oK, _Float16* __restrict__ oV,
    int K, int lda, int ldb, int ldc, int bmask, float alpha,
    long sAz, long sBz, long sCz)
{
    constexpr int BN = 256, BK = 64;
    constexpr int LPT = (BM + BN) / 64;  // global_load_lds per thread per K-tile
    constexpr int MQ = BM / 128;         // m-frags per phase
    constexpr int MF = BM / 32;          // m-frags per wave

    __shared__ __attribute__((aligned(16))) _Float16 lds[2][(BM + BN) * BK];

    const int z = blockIdx.z;
    A += (long)z * sAz;
    const _Float16* B = (OMODE == 1) ? (z == 0 ? Bq : (z == 1 ? Bk : Bv))
                                     : Bq + (long)z * sBz;

    const int tid = threadIdx.x;
    const int lane = tid & 63;
    const int wv = tid >> 6;
    const int wr = wv >> 2, wc = wv & 3;   // 2x4 wave grid
    const int lr = lane & 15, lk = lane >> 4;

    const long m0 = (long)blockIdx.y * BM;
    const long n0 = (long)blockIdx.x * BN;

    fx4 acc[MF][4] = {};

    // stage K-tile at element offset kt into buffer b.
    // LDS dest is linear (global_load_lds); source col pre-swizzled by the
    // same involution the reads use: slot ^= (row & 7).
    auto STAGE = [&](int kt, int b) {
        const int kb = kt & bmask;
#pragma unroll
        for (int i = 0; i < LPT; ++i) {
            const int c = i * 512 + tid;
            if (i < BM / 64) {           // A chunks (compile-time per i)
                const int row = c >> 3, slot = c & 7;
                load_lds16(A + (m0 + row) * (long)lda + kt + ((slot ^ (row & 7)) << 3),
                           &lds[b][c * 8]);
            } else {                     // B chunks
                const int c2 = c - BM * 8;
                const int row = c2 >> 3, slot = c2 & 7;
                load_lds16(B + (n0 + row) * (long)ldb + kb + ((slot ^ (row & 7)) << 3),
                           &lds[b][BM * BK + c2 * 8]);
            }
        }
    };

    const int NT = K / BK;
    STAGE(0, 0);
    STAGE(BK, 1);
    vmwait<LPT>();                       // tile 0 landed, tile 1 in flight
    __builtin_amdgcn_s_barrier();
    __builtin_amdgcn_sched_barrier(0);

    const int rA0 = wr * (BM / 2) + lr;
    const int rB0 = wc * 64 + lr;
    const int eA = (rA0 & 7) << 3;       // swizzle offsets (row&7 invariant +16k)
    const int eB = (rB0 & 7) << 3;

    for (int t = 0; t < NT; ++t) {
        const _Float16* LA = &lds[t & 1][0];
        const _Float16* LB = LA + BM * BK;

        hfx8 bfr[4][2];
#pragma unroll
        for (int nf = 0; nf < 4; ++nf)
#pragma unroll
            for (int ks = 0; ks < 2; ++ks)
                bfr[nf][ks] = *(const hfx8*)&LB[(rB0 + nf * 16) * BK + ((ks * 32 + lk * 8) ^ eB)];

#pragma unroll
        for (int q = 0; q < 4; ++q) {
            hfx8 afr[MQ][2];
#pragma unroll
            for (int mq = 0; mq < MQ; ++mq)
#pragma unroll
                for (int ks = 0; ks < 2; ++ks)
                    afr[mq][ks] = *(const hfx8*)&LA[(rA0 + (q * MQ + mq) * 16) * BK + ((ks * 32 + lk * 8) ^ eA)];
            __builtin_amdgcn_s_setprio(1);
#pragma unroll
            for (int mq = 0; mq < MQ; ++mq)
#pragma unroll
                for (int nf = 0; nf < 4; ++nf)
#pragma unroll
                    for (int ks = 0; ks < 2; ++ks)
                        acc[q * MQ + mq][nf] = __builtin_amdgcn_mfma_f32_16x16x32_f16(
                            afr[mq][ks], bfr[nf][ks], acc[q * MQ + mq][nf], 0, 0, 0);
            __builtin_amdgcn_s_setprio(0);
        }

        __builtin_amdgcn_s_barrier();    // all waves done reading buf (t&1)
        if (t + 2 < NT) {
            STAGE((t + 2) * BK, t & 1);  // refill just-freed buffer
            vmwait<LPT>();               // tile t+1 landed; t+2 stays in flight
        } else {
            vmwait<0>();                 // tail drain (once)
        }
        __builtin_amdgcn_s_barrier();    // all waves see tile t+1 landed
        __builtin_amdgcn_sched_barrier(0);
    }

    // epilogue. D frag: col = lane&15, row = lk*4 + j
#pragma unroll
    for (int mf = 0; mf < MF; ++mf) {
#pragma unroll
        for (int nf = 0; nf < 4; ++nf) {
            const long row0 = m0 + wr * (BM / 2) + mf * 16 + lk * 4;
            const long col = n0 + wc * 64 + nf * 16 + lr;
            if constexpr (OMODE == 0) {
                float* oz = outF + (long)z * sCz;
#pragma unroll
                for (int j = 0; j < 4; ++j)
                    oz[(row0 + j) * (long)ldc + col] = alpha * acc[mf][nf][j];
            } else {
                if (z == 0) {
                    const float bb = bq[col];
#pragma unroll
                    for (int j = 0; j < 4; ++j) {
                        float v = acc[mf][nf][j] + bb;
                        _Float16 h = (_Float16)v;
                        long idx = (row0 + j) * 2048 + col;
                        oQ[idx] = h;
                        oQ[idx + 1024] = (_Float16)(v - (float)h);
                    }
                } else if (z == 1) {
                    const float bb = bk[col];
#pragma unroll
                    for (int j = 0; j < 4; ++j)
                        oK[(row0 + j) * 1024 + col] = (_Float16)(acc[mf][nf][j] + bb);
                } else {
                    const float bb = bv[col];
                    hfx4 pk;
#pragma unroll
                    for (int j = 0; j < 4; ++j) pk[j] = (_Float16)(acc[mf][nf][j] + bb);
                    *(hfx4*)&oV[((row0 >> 11) * 1024 + col) * 2048 + (row0 & 2047)] = pk;
                }
            }
        }
    }
}

// ---------------------------------------------------------------------------
// Row softmax over 2048 fp32, write fp16 probs IN PLACE. One block per row.
// ---------------------------------------------------------------------------
__global__ __launch_bounds__(256) void softmax_kernel(float* __restrict__ S)
{
    const long row = blockIdx.x;
    float* r = S + row * 2048;
    const int t = threadIdx.x;

    float4 v0 = *(const float4*)&r[t * 4];
    float4 v1 = *(const float4*)&r[1024 + t * 4];
    float v[8] = {v0.x, v0.y, v0.z, v0.w, v1.x, v1.y, v1.z, v1.w};

    float mx = v[0];
#pragma unroll
    for (int j = 1; j < 8; ++j) mx = fmaxf(mx, v[j]);
#pragma unroll
    for (int o = 32; o; o >>= 1) mx = fmaxf(mx, __shfl_xor(mx, o, 64));

    __shared__ float redm[4];
    __shared__ float reds[4];
    const int w = t >> 6;
    if ((t & 63) == 0) redm[w] = mx;
    __syncthreads();
    mx = fmaxf(fmaxf(redm[0], redm[1]), fmaxf(redm[2], redm[3]));

    float e[8];
    float s = 0.f;
#pragma unroll
    for (int j = 0; j < 8; ++j) {
        e[j] = __expf(v[j] - mx);
        s += e[j];
    }
#pragma unroll
    for (int o = 32; o; o >>= 1) s += __shfl_xor(s, o, 64);
    if ((t & 63) == 0) reds[w] = s;
    __syncthreads();
    s = reds[0] + reds[1] + reds[2] + reds[3];

    const float inv = 1.0f / s;
    hfx4 p0, p1;
#pragma unroll
    for (int j = 0; j < 4; ++j) {
        p0[j] = (_Float16)(e[j] * inv);
        p1[j] = (_Float16)(e[4 + j] * inv);
    }
    _Float16* pr = (_Float16*)r;
    *(hfx4*)&pr[t * 4] = p0;
    *(hfx4*)&pr[1024 + t * 4] = p1;
}

// ---------------------------------------------------------------------------
extern "C" void kernel_launch(void* const* d_in, const int* in_sizes, int n_in,
                              void* d_out, int out_size, void* d_ws, size_t ws_size,
                              hipStream_t stream)
{
    const float* x  = (const float*)d_in[0];
    const float* Wq = (const float*)d_in[1];
    const float* bq = (const float*)d_in[2];
    const float* Wk = (const float*)d_in[3];
    const float* bk = (const float*)d_in[4];
    const float* Wv = (const float*)d_in[5];
    const float* bv = (const float*)d_in[6];
    float* out = (float*)d_out;

    _Float16* xs  = (_Float16*)d_ws;            // [8192][2048] 32 MB
    _Float16* Wqh = xs + 8192ull * 2048;        // [1024][1024] 2 MB each
    _Float16* Wkh = Wqh + 1024ull * 1024;
    _Float16* Wvh = Wkh + 1024ull * 1024;
    _Float16* Qs  = Wvh + 1024ull * 1024;       // [8192][2048] hi|lo 32 MB
    _Float16* Ks  = Qs + 4ull * 2048 * 2048;    // [8192][1024] 16 MB
    _Float16* Vt  = Ks + 4ull * 2048 * 1024;    // [4][1024][2048] 16 MB
    float* S      = (float*)(Vt + 4ull * 1024 * 2048);  // [4][2048][2048] 64 MB

    dim3 blk(256);
    const int NOMASK = 0x7fffffff;

    // 1) converts
    splitx_kernel<<<8192, blk, 0, stream>>>((const float4*)x, xs);
    convw_kernel<<<1024, blk, 0, stream>>>((const float4*)Wq, Wqh, 262144);
    convw_kernel<<<1024, blk, 0, stream>>>((const float4*)Wk, Wkh, 262144);
    convw_kernel<<<1024, blk, 0, stream>>>((const float4*)Wv, Wvh, 262144);

    // 2) projections: one z=3 dispatch, all 2-term (K'=2048, bmask=1023)
    gemm2<256, 1><<<dim3(4, 32, 3), 512, 0, stream>>>(
        xs, Wqh, Wkh, Wvh, bq, bk, bv,
        nullptr, Qs, Ks, Vt,
        2048, 2048, 1024, 0, 1023, 1.0f, 0L, 0L, 0L);

    // 3) scores: [Qh|Ql] @ [K|K]^T, fp32 out, z=4  (8x8x4 = 256 blocks)
    gemm2<256, 0><<<dim3(8, 8, 4), 512, 0, stream>>>(
        Qs, Ks, nullptr, nullptr, nullptr, nullptr, nullptr,
        S, nullptr, nullptr, nullptr,
        2048, 2048, 1024, 2048, 1023, 1.0f,
        4194304L, 2097152L, 4194304L);

    // 4) softmax (P fp16 in place)
    softmax_kernel<<<2048 * 4, blk, 0, stream>>>(S);

    // 5) PV: P @ Vt^T, alpha = 1/32, fp32 out, z=4  (4x16x4 = 256 blocks)
    gemm2<128, 0><<<dim3(4, 16, 4), 512, 0, stream>>>(
        (const _Float16*)S, Vt, nullptr, nullptr, nullptr, nullptr, nullptr,
        out, nullptr, nullptr, nullptr,
        2048, 4096, 2048, 1024, NOMASK, 0.03125f,
        8388608L, 2097152L, 2097152L);
}

// Round 5
// 264.758 us; speedup vs baseline: 2.2280x; 1.0549x over previous
//
#include <hip/hip_runtime.h>

// ---------------------------------------------------------------------------
// Self-attention (B=4, N=2048, D=1024) on MI355X — fp16 pipeline, round 5:
// counted-vmcnt double-buffered GEMM (T2+T4+T5), templated wave grid.
// Proj reshaped to 768-block no-tail dispatch; V projection 1-term.
// ---------------------------------------------------------------------------

typedef _Float16 hfx8 __attribute__((ext_vector_type(8)));
typedef _Float16 hfx4 __attribute__((ext_vector_type(4)));
typedef float fx4 __attribute__((ext_vector_type(4)));

__device__ __forceinline__ void load_lds16(const void* g, void* l) {
    __builtin_amdgcn_global_load_lds(
        (const __attribute__((address_space(1))) void*)g,
        (__attribute__((address_space(3))) void*)l, 16, 0, 0);
}

template <int N> __device__ __forceinline__ void vmwait() {
    if constexpr (N == 8) asm volatile("s_waitcnt vmcnt(8)" ::: "memory");
    else if constexpr (N == 6) asm volatile("s_waitcnt vmcnt(6)" ::: "memory");
    else asm volatile("s_waitcnt vmcnt(0)" ::: "memory");
}

// ---------------------------------------------------------------------------
// x fp32 [8192][1024] -> xs fp16 [8192][2048], row = [hi(1024) | lo(1024)]
// ---------------------------------------------------------------------------
__global__ __launch_bounds__(256) void splitx_kernel(
    const float4* __restrict__ in, _Float16* __restrict__ xs)
{
    const int i = blockIdx.x * 256 + threadIdx.x;
    const long row = i >> 8;
    const int c4 = (i & 255) * 4;
    float4 v = in[i];
    float vv[4] = {v.x, v.y, v.z, v.w};
    hfx4 h, l;
#pragma unroll
    for (int j = 0; j < 4; ++j) {
        h[j] = (_Float16)vv[j];
        l[j] = (_Float16)(vv[j] - (float)h[j]);
    }
    *(hfx4*)&xs[row * 2048 + c4] = h;
    *(hfx4*)&xs[row * 2048 + 1024 + c4] = l;
}

// three weight matrices fp32 -> fp16 in one dispatch (3 x 1024 blocks)
__global__ __launch_bounds__(256) void convw3_kernel(
    const float4* __restrict__ w0, const float4* __restrict__ w1, const float4* __restrict__ w2,
    _Float16* __restrict__ o0, _Float16* __restrict__ o1, _Float16* __restrict__ o2)
{
    const int wsel = blockIdx.x >> 10;
    const float4* in = wsel == 0 ? w0 : (wsel == 1 ? w1 : w2);
    _Float16* out = wsel == 0 ? o0 : (wsel == 1 ? o1 : o2);
    const int i = (blockIdx.x & 1023) * 256 + threadIdx.x;
    float4 v = in[i];
    hfx4 h;
    h[0] = (_Float16)v.x; h[1] = (_Float16)v.y;
    h[2] = (_Float16)v.z; h[3] = (_Float16)v.w;
    *(hfx4*)&out[(long)i * 4] = h;
}

// ---------------------------------------------------------------------------
// Pipelined GEMM. BK=64, 512 threads = 8 waves, wave grid WM x WN
// (WM=4,WN=2 when BN==128 else 2x4). LDS: 2 x (BM+BN) x 64 fp16.
// A [M x K'] row-major lda; B [N x K'] row-major ldb with k & bmask.
// OMODE 0: fp32 out = alpha*acc -> outF + z*sCz (ldc)
// OMODE 1: projections, z: 0 = Q split (oQ [8192][2048] hi|lo, K'=2048),
//          1 = K plain (oK [8192][1024], K'=2048),
//          2 = V transposed 1-term (oV [4][1024][2048], K'=1024)
// ---------------------------------------------------------------------------
template <int BM, int BN, int OMODE>
__global__ __launch_bounds__(512, 2) void gemm2(
    const _Float16* __restrict__ A,
    const _Float16* __restrict__ Bq, const _Float16* __restrict__ Bk, const _Float16* __restrict__ Bv,
    const float* __restrict__ bq, const float* __restrict__ bk, const float* __restrict__ bv,
    float* __restrict__ outF, _Float16* __restrict__ oQ, _Float16* __restrict__ oK, _Float16* __restrict__ oV,
    int K, int lda, int ldb, int ldc, int bmask, float alpha,
    long sAz, long sBz, long sCz)
{
    constexpr int BK = 64;
    constexpr int LPT = (BM + BN) / 64;     // global_load_lds per thread per K-tile
    constexpr int WN = (BN == 128) ? 2 : 4;
    constexpr int WM = 8 / WN;
    constexpr int RM = BM / WM, RN = BN / WN;
    constexpr int MF = RM / 16, NF = RN / 16;  // NF == 4 in all instantiations
    constexpr int MQ = MF / 4;              // m-frags per phase (4 phases)

    __shared__ __attribute__((aligned(16))) _Float16 lds[2][(BM + BN) * BK];

    const int z = blockIdx.z;
    A += (long)z * sAz;
    const _Float16* B = (OMODE == 1) ? (z == 0 ? Bq : (z == 1 ? Bk : Bv))
                                     : Bq + (long)z * sBz;
    const int Kz = (OMODE == 1 && z == 2) ? 1024 : K;

    const int tid = threadIdx.x;
    const int lane = tid & 63;
    const int wv = tid >> 6;
    const int wr = wv / WN, wc = wv % WN;
    const int lr = lane & 15, lk = lane >> 4;

    const long m0 = (long)blockIdx.y * BM;
    const long n0 = (long)blockIdx.x * BN;

    fx4 acc[MF][4] = {};

    // stage K-tile at element offset kt into buffer b. Linear LDS dest;
    // source col pre-swizzled by the involution the reads use (rule #21).
    auto STAGE = [&](int kt, int b) {
        const int kb = kt & bmask;
#pragma unroll
        for (int i = 0; i < LPT; ++i) {
            const int c = i * 512 + tid;
            if (i < BM / 64) {              // A chunks
                const int row = c >> 3, slot = c & 7;
                load_lds16(A + (m0 + row) * (long)lda + kt + ((slot ^ (row & 7)) << 3),
                           &lds[b][c * 8]);
            } else {                        // B chunks
                const int c2 = c - BM * 8;
                const int row = c2 >> 3, slot = c2 & 7;
                load_lds16(B + (n0 + row) * (long)ldb + kb + ((slot ^ (row & 7)) << 3),
                           &lds[b][BM * BK + c2 * 8]);
            }
        }
    };

    const int NT = Kz / BK;
    STAGE(0, 0);
    STAGE(BK, 1);
    vmwait<LPT>();                          // tile 0 landed, tile 1 in flight
    __builtin_amdgcn_s_barrier();
    __builtin_amdgcn_sched_barrier(0);

    const int rA0 = wr * RM + lr;
    const int rB0 = wc * RN + lr;
    const int eA = (rA0 & 7) << 3;
    const int eB = (rB0 & 7) << 3;

    for (int t = 0; t < NT; ++t) {
        const _Float16* LA = &lds[t & 1][0];
        const _Float16* LB = LA + BM * BK;

        hfx8 bfr[4][2];
#pragma unroll
        for (int nf = 0; nf < 4; ++nf)
#pragma unroll
            for (int ks = 0; ks < 2; ++ks)
                bfr[nf][ks] = *(const hfx8*)&LB[(rB0 + nf * 16) * BK + ((ks * 32 + lk * 8) ^ eB)];

#pragma unroll
        for (int q = 0; q < 4; ++q) {
            hfx8 afr[MQ][2];
#pragma unroll
            for (int mq = 0; mq < MQ; ++mq)
#pragma unroll
                for (int ks = 0; ks < 2; ++ks)
                    afr[mq][ks] = *(const hfx8*)&LA[(rA0 + (q * MQ + mq) * 16) * BK + ((ks * 32 + lk * 8) ^ eA)];
            __builtin_amdgcn_s_setprio(1);
#pragma unroll
            for (int mq = 0; mq < MQ; ++mq)
#pragma unroll
                for (int nf = 0; nf < 4; ++nf)
#pragma unroll
                    for (int ks = 0; ks < 2; ++ks)
                        acc[q * MQ + mq][nf] = __builtin_amdgcn_mfma_f32_16x16x32_f16(
                            afr[mq][ks], bfr[nf][ks], acc[q * MQ + mq][nf], 0, 0, 0);
            __builtin_amdgcn_s_setprio(0);
        }

        __builtin_amdgcn_s_barrier();       // all waves done reading buf (t&1)
        if (t + 2 < NT) {
            STAGE((t + 2) * BK, t & 1);     // refill just-freed buffer
            vmwait<LPT>();                  // tile t+1 landed; t+2 in flight
        } else {
            vmwait<0>();                    // tail drain
        }
        __builtin_amdgcn_s_barrier();       // all waves see tile t+1 landed
        __builtin_amdgcn_sched_barrier(0);
    }

    // epilogue. D frag: col = lane&15, row = lk*4 + j
#pragma unroll
    for (int mf = 0; mf < MF; ++mf) {
#pragma unroll
        for (int nf = 0; nf < 4; ++nf) {
            const long row0 = m0 + wr * RM + mf * 16 + lk * 4;
            const long col = n0 + wc * RN + nf * 16 + lr;
            if constexpr (OMODE == 0) {
                float* oz = outF + (long)z * sCz;
#pragma unroll
                for (int j = 0; j < 4; ++j)
                    oz[(row0 + j) * (long)ldc + col] = alpha * acc[mf][nf][j];
            } else {
                if (z == 0) {
                    const float bb = bq[col];
#pragma unroll
                    for (int j = 0; j < 4; ++j) {
                        float v = acc[mf][nf][j] + bb;
                        _Float16 h = (_Float16)v;
                        long idx = (row0 + j) * 2048 + col;
                        oQ[idx] = h;
                        oQ[idx + 1024] = (_Float16)(v - (float)h);
                    }
                } else if (z == 1) {
                    const float bb = bk[col];
#pragma unroll
                    for (int j = 0; j < 4; ++j)
                        oK[(row0 + j) * 1024 + col] = (_Float16)(acc[mf][nf][j] + bb);
                } else {
                    const float bb = bv[col];
                    hfx4 pk;
#pragma unroll
                    for (int j = 0; j < 4; ++j) pk[j] = (_Float16)(acc[mf][nf][j] + bb);
                    *(hfx4*)&oV[((row0 >> 11) * 1024 + col) * 2048 + (row0 & 2047)] = pk;
                }
            }
        }
    }
}

// ---------------------------------------------------------------------------
// Row softmax over 2048 fp32, write fp16 probs IN PLACE. One block per row.
// ---------------------------------------------------------------------------
__global__ __launch_bounds__(256) void softmax_kernel(float* __restrict__ S)
{
    const long row = blockIdx.x;
    float* r = S + row * 2048;
    const int t = threadIdx.x;

    float4 v0 = *(const float4*)&r[t * 4];
    float4 v1 = *(const float4*)&r[1024 + t * 4];
    float v[8] = {v0.x, v0.y, v0.z, v0.w, v1.x, v1.y, v1.z, v1.w};

    float mx = v[0];
#pragma unroll
    for (int j = 1; j < 8; ++j) mx = fmaxf(mx, v[j]);
#pragma unroll
    for (int o = 32; o; o >>= 1) mx = fmaxf(mx, __shfl_xor(mx, o, 64));

    __shared__ float redm[4];
    __shared__ float reds[4];
    const int w = t >> 6;
    if ((t & 63) == 0) redm[w] = mx;
    __syncthreads();
    mx = fmaxf(fmaxf(redm[0], redm[1]), fmaxf(redm[2], redm[3]));

    float e[8];
    float s = 0.f;
#pragma unroll
    for (int j = 0; j < 8; ++j) {
        e[j] = __expf(v[j] - mx);
        s += e[j];
    }
#pragma unroll
    for (int o = 32; o; o >>= 1) s += __shfl_xor(s, o, 64);
    if ((t & 63) == 0) reds[w] = s;
    __syncthreads();
    s = reds[0] + reds[1] + reds[2] + reds[3];

    const float inv = 1.0f / s;
    hfx4 p0, p1;
#pragma unroll
    for (int j = 0; j < 4; ++j) {
        p0[j] = (_Float16)(e[j] * inv);
        p1[j] = (_Float16)(e[4 + j] * inv);
    }
    _Float16* pr = (_Float16*)r;
    *(hfx4*)&pr[t * 4] = p0;
    *(hfx4*)&pr[1024 + t * 4] = p1;
}

// ---------------------------------------------------------------------------
extern "C" void kernel_launch(void* const* d_in, const int* in_sizes, int n_in,
                              void* d_out, int out_size, void* d_ws, size_t ws_size,
                              hipStream_t stream)
{
    const float* x  = (const float*)d_in[0];
    const float* Wq = (const float*)d_in[1];
    const float* bq = (const float*)d_in[2];
    const float* Wk = (const float*)d_in[3];
    const float* bk = (const float*)d_in[4];
    const float* Wv = (const float*)d_in[5];
    const float* bv = (const float*)d_in[6];
    float* out = (float*)d_out;

    _Float16* xs  = (_Float16*)d_ws;            // [8192][2048] 32 MB
    _Float16* Wqh = xs + 8192ull * 2048;        // [1024][1024] 2 MB each
    _Float16* Wkh = Wqh + 1024ull * 1024;
    _Float16* Wvh = Wkh + 1024ull * 1024;
    _Float16* Qs  = Wvh + 1024ull * 1024;       // [8192][2048] hi|lo 32 MB
    _Float16* Ks  = Qs + 4ull * 2048 * 2048;    // [8192][1024] 16 MB
    _Float16* Vt  = Ks + 4ull * 2048 * 1024;    // [4][1024][2048] 16 MB
    float* S      = (float*)(Vt + 4ull * 1024 * 2048);  // [4][2048][2048] 64 MB

    dim3 blk(256);
    const int NOMASK = 0x7fffffff;

    // 1) converts
    splitx_kernel<<<8192, blk, 0, stream>>>((const float4*)x, xs);
    convw3_kernel<<<3072, blk, 0, stream>>>(
        (const float4*)Wq, (const float4*)Wk, (const float4*)Wv, Wqh, Wkh, Wvh);

    // 2) projections: 8 x 32 x 3 = 768 blocks = exactly 3 scheduling waves.
    //    z=0: Q 2-term split-out; z=1: K 2-term; z=2: V 1-term transposed.
    gemm2<256, 128, 1><<<dim3(8, 32, 3), 512, 0, stream>>>(
        xs, Wqh, Wkh, Wvh, bq, bk, bv,
        nullptr, Qs, Ks, Vt,
        2048, 2048, 1024, 0, 1023, 1.0f, 0L, 0L, 0L);

    // 3) scores: [Qh|Ql] @ [K|K]^T, fp32 out, z=4  (8x8x4 = 256 blocks)
    gemm2<256, 256, 0><<<dim3(8, 8, 4), 512, 0, stream>>>(
        Qs, Ks, nullptr, nullptr, nullptr, nullptr, nullptr,
        S, nullptr, nullptr, nullptr,
        2048, 2048, 1024, 2048, 1023, 1.0f,
        4194304L, 2097152L, 4194304L);

    // 4) softmax (P fp16 in place)
    softmax_kernel<<<2048 * 4, blk, 0, stream>>>(S);

    // 5) PV: P @ Vt^T, alpha = 1/32, fp32 out, z=4  (4x16x4 = 256 blocks)
    gemm2<128, 256, 0><<<dim3(4, 16, 4), 512, 0, stream>>>(
        (const _Float16*)S, Vt, nullptr, nullptr, nullptr, nullptr, nullptr,
        out, nullptr, nullptr, nullptr,
        2048, 4096, 2048, 1024, NOMASK, 0.03125f,
        8388608L, 2097152L, 2097152L);
}

// Round 6
// 251.656 us; speedup vs baseline: 2.3440x; 1.0521x over previous
//
#include <hip/hip_runtime.h>

// ---------------------------------------------------------------------------
// Self-attention (B=4, N=2048, D=1024) on MI355X — fp16 pipeline, round 6:
// 128x128/BK=64 counted-vmcnt double-buffered GEMM (T2+T4+T5), 256 threads,
// 64 KB LDS -> 2 blocks/CU (m114 overlap), bijective XCD swizzle (T1).
// ---------------------------------------------------------------------------

typedef _Float16 hfx8 __attribute__((ext_vector_type(8)));
typedef _Float16 hfx4 __attribute__((ext_vector_type(4)));
typedef float fx4 __attribute__((ext_vector_type(4)));

__device__ __forceinline__ void load_lds16(const void* g, void* l) {
    __builtin_amdgcn_global_load_lds(
        (const __attribute__((address_space(1))) void*)g,
        (__attribute__((address_space(3))) void*)l, 16, 0, 0);
}

template <int N> __device__ __forceinline__ void vmwait() {
    if constexpr (N == 8) asm volatile("s_waitcnt vmcnt(8)" ::: "memory");
    else if constexpr (N == 6) asm volatile("s_waitcnt vmcnt(6)" ::: "memory");
    else asm volatile("s_waitcnt vmcnt(0)" ::: "memory");
}

// bijective XCD-chunked grid remap (T1, m204). Requires nwg % 8 == 0.
__device__ __forceinline__ void xcd_remap(int& x, int& y, int& z) {
    const int gx = gridDim.x, gy = gridDim.y;
    const int lin = blockIdx.x + gx * (blockIdx.y + gy * blockIdx.z);
    const int cpx = (gx * gy * gridDim.z) >> 3;
    const int w = (lin & 7) * cpx + (lin >> 3);
    x = w % gx;
    y = (w / gx) % gy;
    z = w / (gx * gy);
}

// ---------------------------------------------------------------------------
// x fp32 [8192][1024] -> xs fp16 [8192][2048], row = [hi(1024) | lo(1024)]
// ---------------------------------------------------------------------------
__global__ __launch_bounds__(256) void splitx_kernel(
    const float4* __restrict__ in, _Float16* __restrict__ xs)
{
    const int i = blockIdx.x * 256 + threadIdx.x;
    const long row = i >> 8;
    const int c4 = (i & 255) * 4;
    float4 v = in[i];
    float vv[4] = {v.x, v.y, v.z, v.w};
    hfx4 h, l;
#pragma unroll
    for (int j = 0; j < 4; ++j) {
        h[j] = (_Float16)vv[j];
        l[j] = (_Float16)(vv[j] - (float)h[j]);
    }
    *(hfx4*)&xs[row * 2048 + c4] = h;
    *(hfx4*)&xs[row * 2048 + 1024 + c4] = l;
}

// three weight matrices fp32 -> fp16 in one dispatch (3 x 1024 blocks)
__global__ __launch_bounds__(256) void convw3_kernel(
    const float4* __restrict__ w0, const float4* __restrict__ w1, const float4* __restrict__ w2,
    _Float16* __restrict__ o0, _Float16* __restrict__ o1, _Float16* __restrict__ o2)
{
    const int wsel = blockIdx.x >> 10;
    const float4* in = wsel == 0 ? w0 : (wsel == 1 ? w1 : w2);
    _Float16* out = wsel == 0 ? o0 : (wsel == 1 ? o1 : o2);
    const int i = (blockIdx.x & 1023) * 256 + threadIdx.x;
    float4 v = in[i];
    hfx4 h;
    h[0] = (_Float16)v.x; h[1] = (_Float16)v.y;
    h[2] = (_Float16)v.z; h[3] = (_Float16)v.w;
    *(hfx4*)&out[(long)i * 4] = h;
}

// ---------------------------------------------------------------------------
// Pipelined GEMM. BM=BN=128, BK=64, 256 threads = 4 waves (2x2), 64 KB LDS
// -> 2 blocks/CU. Counted-vmcnt double-buffer, raw s_barrier only.
// A [M x K'] row-major lda; B [N x K'] row-major ldb with k & bmask.
// OMODE 0: fp32 out = alpha*acc -> outF + z*sCz (ldc)
// OMODE 1: projections, z: 0 = Q split (oQ [8192][2048] hi|lo, K'=2048),
//          1 = K plain (oK [8192][1024], K'=2048),
//          2 = V transposed 1-term (oV [4][1024][2048], K'=1024)
// ---------------------------------------------------------------------------
template <int OMODE>
__global__ __launch_bounds__(256, 2) void gemm2(
    const _Float16* __restrict__ A,
    const _Float16* __restrict__ Bq, const _Float16* __restrict__ Bk, const _Float16* __restrict__ Bv,
    const float* __restrict__ bq, const float* __restrict__ bk, const float* __restrict__ bv,
    float* __restrict__ outF, _Float16* __restrict__ oQ, _Float16* __restrict__ oK, _Float16* __restrict__ oV,
    int K, int lda, int ldb, int ldc, int bmask, float alpha,
    long sAz, long sBz, long sCz)
{
    constexpr int BM = 128, BN = 128, BK = 64;
    constexpr int LPT = 8;   // global_load_lds per thread per K-tile

    __shared__ __attribute__((aligned(16))) _Float16 lds[2][(BM + BN) * BK];

    int bx, by, z;
    xcd_remap(bx, by, z);

    A += (long)z * sAz;
    const _Float16* B = (OMODE == 1) ? (z == 0 ? Bq : (z == 1 ? Bk : Bv))
                                     : Bq + (long)z * sBz;
    const int Kz = (OMODE == 1 && z == 2) ? 1024 : K;

    const int tid = threadIdx.x;
    const int lane = tid & 63;
    const int wv = tid >> 6;
    const int wr = wv >> 1, wc = wv & 1;   // 2x2 wave grid, 64x64 out each
    const int lr = lane & 15, lk = lane >> 4;

    const long m0 = (long)by * BM;
    const long n0 = (long)bx * BN;

    fx4 acc[4][4] = {};

    // stage K-tile at element offset kt into buffer b. Linear LDS dest;
    // source col pre-swizzled by the involution the reads use (rule #21).
    auto STAGE = [&](int kt, int b) {
        const int kb = kt & bmask;
#pragma unroll
        for (int i = 0; i < LPT; ++i) {
            const int c = i * 256 + tid;
            if (i < 4) {                    // A chunks: 128 rows x 8 slots
                const int row = c >> 3, slot = c & 7;
                load_lds16(A + (m0 + row) * (long)lda + kt + ((slot ^ (row & 7)) << 3),
                           &lds[b][c * 8]);
            } else {                        // B chunks
                const int c2 = c - 1024;
                const int row = c2 >> 3, slot = c2 & 7;
                load_lds16(B + (n0 + row) * (long)ldb + kb + ((slot ^ (row & 7)) << 3),
                           &lds[b][BM * BK + c2 * 8]);
            }
        }
    };

    const int NT = Kz / BK;
    STAGE(0, 0);
    STAGE(BK, 1);
    vmwait<LPT>();                          // tile 0 landed, tile 1 in flight
    __builtin_amdgcn_s_barrier();
    __builtin_amdgcn_sched_barrier(0);

    const int rA0 = wr * 64 + lr;
    const int rB0 = wc * 64 + lr;
    const int eA = (rA0 & 7) << 3;
    const int eB = (rB0 & 7) << 3;

    for (int t = 0; t < NT; ++t) {
        const _Float16* LA = &lds[t & 1][0];
        const _Float16* LB = LA + BM * BK;

        hfx8 bfr[4][2];
#pragma unroll
        for (int nf = 0; nf < 4; ++nf)
#pragma unroll
            for (int ks = 0; ks < 2; ++ks)
                bfr[nf][ks] = *(const hfx8*)&LB[(rB0 + nf * 16) * BK + ((ks * 32 + lk * 8) ^ eB)];

#pragma unroll
        for (int q = 0; q < 4; ++q) {
            hfx8 afr[2];
#pragma unroll
            for (int ks = 0; ks < 2; ++ks)
                afr[ks] = *(const hfx8*)&LA[(rA0 + q * 16) * BK + ((ks * 32 + lk * 8) ^ eA)];
            __builtin_amdgcn_s_setprio(1);
#pragma unroll
            for (int nf = 0; nf < 4; ++nf)
#pragma unroll
                for (int ks = 0; ks < 2; ++ks)
                    acc[q][nf] = __builtin_amdgcn_mfma_f32_16x16x32_f16(
                        afr[ks], bfr[nf][ks], acc[q][nf], 0, 0, 0);
            __builtin_amdgcn_s_setprio(0);
        }

        __builtin_amdgcn_s_barrier();       // all waves done reading buf (t&1)
        if (t + 2 < NT) {
            STAGE((t + 2) * BK, t & 1);     // refill just-freed buffer
            vmwait<LPT>();                  // tile t+1 landed; t+2 in flight
        } else {
            vmwait<0>();                    // tail drain
        }
        __builtin_amdgcn_s_barrier();       // all waves see tile t+1 landed
        __builtin_amdgcn_sched_barrier(0);
    }

    // epilogue. D frag: col = lane&15, row = lk*4 + j
#pragma unroll
    for (int mf = 0; mf < 4; ++mf) {
#pragma unroll
        for (int nf = 0; nf < 4; ++nf) {
            const long row0 = m0 + wr * 64 + mf * 16 + lk * 4;
            const long col = n0 + wc * 64 + nf * 16 + lr;
            if constexpr (OMODE == 0) {
                float* oz = outF + (long)z * sCz;
#pragma unroll
                for (int j = 0; j < 4; ++j)
                    oz[(row0 + j) * (long)ldc + col] = alpha * acc[mf][nf][j];
            } else {
                if (z == 0) {
                    const float bb = bq[col];
#pragma unroll
                    for (int j = 0; j < 4; ++j) {
                        float v = acc[mf][nf][j] + bb;
                        _Float16 h = (_Float16)v;
                        long idx = (row0 + j) * 2048 + col;
                        oQ[idx] = h;
                        oQ[idx + 1024] = (_Float16)(v - (float)h);
                    }
                } else if (z == 1) {
                    const float bb = bk[col];
#pragma unroll
                    for (int j = 0; j < 4; ++j)
                        oK[(row0 + j) * 1024 + col] = (_Float16)(acc[mf][nf][j] + bb);
                } else {
                    const float bb = bv[col];
                    hfx4 pk;
#pragma unroll
                    for (int j = 0; j < 4; ++j) pk[j] = (_Float16)(acc[mf][nf][j] + bb);
                    *(hfx4*)&oV[((row0 >> 11) * 1024 + col) * 2048 + (row0 & 2047)] = pk;
                }
            }
        }
    }
}

// ---------------------------------------------------------------------------
// Row softmax over 2048 fp32, write fp16 probs IN PLACE. One block per row.
// ---------------------------------------------------------------------------
__global__ __launch_bounds__(256) void softmax_kernel(float* __restrict__ S)
{
    const long row = blockIdx.x;
    float* r = S + row * 2048;
    const int t = threadIdx.x;

    float4 v0 = *(const float4*)&r[t * 4];
    float4 v1 = *(const float4*)&r[1024 + t * 4];
    float v[8] = {v0.x, v0.y, v0.z, v0.w, v1.x, v1.y, v1.z, v1.w};

    float mx = v[0];
#pragma unroll
    for (int j = 1; j < 8; ++j) mx = fmaxf(mx, v[j]);
#pragma unroll
    for (int o = 32; o; o >>= 1) mx = fmaxf(mx, __shfl_xor(mx, o, 64));

    __shared__ float redm[4];
    __shared__ float reds[4];
    const int w = t >> 6;
    if ((t & 63) == 0) redm[w] = mx;
    __syncthreads();
    mx = fmaxf(fmaxf(redm[0], redm[1]), fmaxf(redm[2], redm[3]));

    float e[8];
    float s = 0.f;
#pragma unroll
    for (int j = 0; j < 8; ++j) {
        e[j] = __expf(v[j] - mx);
        s += e[j];
    }
#pragma unroll
    for (int o = 32; o; o >>= 1) s += __shfl_xor(s, o, 64);
    if ((t & 63) == 0) reds[w] = s;
    __syncthreads();
    s = reds[0] + reds[1] + reds[2] + reds[3];

    const float inv = 1.0f / s;
    hfx4 p0, p1;
#pragma unroll
    for (int j = 0; j < 4; ++j) {
        p0[j] = (_Float16)(e[j] * inv);
        p1[j] = (_Float16)(e[4 + j] * inv);
    }
    _Float16* pr = (_Float16*)r;
    *(hfx4*)&pr[t * 4] = p0;
    *(hfx4*)&pr[1024 + t * 4] = p1;
}

// ---------------------------------------------------------------------------
extern "C" void kernel_launch(void* const* d_in, const int* in_sizes, int n_in,
                              void* d_out, int out_size, void* d_ws, size_t ws_size,
                              hipStream_t stream)
{
    const float* x  = (const float*)d_in[0];
    const float* Wq = (const float*)d_in[1];
    const float* bq = (const float*)d_in[2];
    const float* Wk = (const float*)d_in[3];
    const float* bk = (const float*)d_in[4];
    const float* Wv = (const float*)d_in[5];
    const float* bv = (const float*)d_in[6];
    float* out = (float*)d_out;

    _Float16* xs  = (_Float16*)d_ws;            // [8192][2048] 32 MB
    _Float16* Wqh = xs + 8192ull * 2048;        // [1024][1024] 2 MB each
    _Float16* Wkh = Wqh + 1024ull * 1024;
    _Float16* Wvh = Wkh + 1024ull * 1024;
    _Float16* Qs  = Wvh + 1024ull * 1024;       // [8192][2048] hi|lo 32 MB
    _Float16* Ks  = Qs + 4ull * 2048 * 2048;    // [8192][1024] 16 MB
    _Float16* Vt  = Ks + 4ull * 2048 * 1024;    // [4][1024][2048] 16 MB
    float* S      = (float*)(Vt + 4ull * 1024 * 2048);  // [4][2048][2048] 64 MB

    dim3 blk(256);
    const int NOMASK = 0x7fffffff;

    // 1) converts
    splitx_kernel<<<8192, blk, 0, stream>>>((const float4*)x, xs);
    convw3_kernel<<<3072, blk, 0, stream>>>(
        (const float4*)Wq, (const float4*)Wk, (const float4*)Wv, Wqh, Wkh, Wvh);

    // 2) projections: 8 x 64 x 3 = 1536 blocks (3 rounds at 2 blocks/CU).
    //    z=0: Q 2-term split-out; z=1: K 2-term; z=2: V 1-term transposed.
    gemm2<1><<<dim3(8, 64, 3), blk, 0, stream>>>(
        xs, Wqh, Wkh, Wvh, bq, bk, bv,
        nullptr, Qs, Ks, Vt,
        2048, 2048, 1024, 0, 1023, 1.0f, 0L, 0L, 0L);

    // 3) scores: [Qh|Ql] @ [K|K]^T, fp32 out, z=4  (16x16x4 = 1024 blocks)
    gemm2<0><<<dim3(16, 16, 4), blk, 0, stream>>>(
        Qs, Ks, nullptr, nullptr, nullptr, nullptr, nullptr,
        S, nullptr, nullptr, nullptr,
        2048, 2048, 1024, 2048, 1023, 1.0f,
        4194304L, 2097152L, 4194304L);

    // 4) softmax (P fp16 in place)
    softmax_kernel<<<2048 * 4, blk, 0, stream>>>(S);

    // 5) PV: P @ Vt^T, alpha = 1/32, fp32 out, z=4  (8x16x4 = 512 blocks)
    gemm2<0><<<dim3(8, 16, 4), blk, 0, stream>>>(
        (const _Float16*)S, Vt, nullptr, nullptr, nullptr, nullptr, nullptr,
        out, nullptr, nullptr, nullptr,
        2048, 4096, 2048, 1024, NOMASK, 0.03125f,
        8388608L, 2097152L, 2097152L);
}